// Round 1
// baseline (1361.354 us; speedup 1.0000x reference)
//
#include <hip/hip_runtime.h>
#include <cstddef>

#define SEQ    2048
#define DMODEL 1024
#define NH     16
#define HD     64
#define NB     2

// ---------------------------------------------------------------------------
// fp32 GEMM: C = A (MxK) * W^T (NxK) + bias, K = 1024.
// BM = BN = 128, BK = 32, 256 threads, 8x8 microtile, k-major LDS tiles so the
// inner loop does float4 LDS reads (ds_read_b128).
// ---------------------------------------------------------------------------

__global__ __launch_bounds__(256)
void gemm_qkv_kernel(const float* __restrict__ A, const float* __restrict__ W,
                     const float* __restrict__ bias,
                     float* __restrict__ qws, float* __restrict__ kws,
                     float* __restrict__ vws)
{
    const int K = DMODEL;
    __shared__ float As[32][132];   // [k][m], stride 132 keeps float4 alignment
    __shared__ float Bs[32][132];   // [k][n]
    const int tid = threadIdx.x;
    const int ty = tid >> 4, tx = tid & 15;
    const int m0 = blockIdx.y * 128;
    const int n0 = blockIdx.x * 128;

    float acc[8][8];
#pragma unroll
    for (int i = 0; i < 8; ++i)
#pragma unroll
        for (int j = 0; j < 8; ++j) acc[i][j] = 0.f;

    for (int k0 = 0; k0 < K; k0 += 32) {
#pragma unroll
        for (int l = 0; l < 4; ++l) {
            int e4  = l * 256 + tid;
            int row = e4 >> 3;
            int c4  = (e4 & 7) << 2;
            float4 av = *(const float4*)&A[(size_t)(m0 + row) * K + k0 + c4];
            As[c4 + 0][row] = av.x; As[c4 + 1][row] = av.y;
            As[c4 + 2][row] = av.z; As[c4 + 3][row] = av.w;
            float4 wv = *(const float4*)&W[(size_t)(n0 + row) * K + k0 + c4];
            Bs[c4 + 0][row] = wv.x; Bs[c4 + 1][row] = wv.y;
            Bs[c4 + 2][row] = wv.z; Bs[c4 + 3][row] = wv.w;
        }
        __syncthreads();
        for (int kk = 0; kk < 32; ++kk) {
            float4 a0 = *(const float4*)&As[kk][8 * ty];
            float4 a1 = *(const float4*)&As[kk][8 * ty + 4];
            float4 b0 = *(const float4*)&Bs[kk][8 * tx];
            float4 b1 = *(const float4*)&Bs[kk][8 * tx + 4];
            float a[8] = {a0.x, a0.y, a0.z, a0.w, a1.x, a1.y, a1.z, a1.w};
            float b[8] = {b0.x, b0.y, b0.z, b0.w, b1.x, b1.y, b1.z, b1.w};
#pragma unroll
            for (int i = 0; i < 8; ++i)
#pragma unroll
                for (int j = 0; j < 8; ++j)
                    acc[i][j] = fmaf(a[i], b[j], acc[i][j]);
        }
        __syncthreads();
    }

    // Epilogue: bias add + scatter into q/k/v laid out (B, H, T, HD)
#pragma unroll
    for (int i = 0; i < 8; ++i) {
        int m = m0 + 8 * ty + i;
        int bb = m >> 11;          // m / SEQ
        int t  = m & 2047;         // m % SEQ
#pragma unroll
        for (int j = 0; j < 8; ++j) {
            int n = n0 + 8 * tx + j;
            float val = acc[i][j] + bias[n];
            int which = n >> 10;       // 0=q 1=k 2=v
            int r = n & 1023;
            int h = r >> 6;
            int d = r & 63;
            size_t idx = (((size_t)bb * NH + h) * SEQ + t) * HD + d;
            if (which == 0)      qws[idx] = val;
            else if (which == 1) kws[idx] = val;
            else                 vws[idx] = val;
        }
    }
}

__global__ __launch_bounds__(256)
void gemm_out_kernel(const float* __restrict__ A, const float* __restrict__ W,
                     const float* __restrict__ bias, float* __restrict__ out)
{
    const int K = DMODEL;
    __shared__ float As[32][132];
    __shared__ float Bs[32][132];
    const int tid = threadIdx.x;
    const int ty = tid >> 4, tx = tid & 15;
    const int m0 = blockIdx.y * 128;
    const int n0 = blockIdx.x * 128;

    float acc[8][8];
#pragma unroll
    for (int i = 0; i < 8; ++i)
#pragma unroll
        for (int j = 0; j < 8; ++j) acc[i][j] = 0.f;

    for (int k0 = 0; k0 < K; k0 += 32) {
#pragma unroll
        for (int l = 0; l < 4; ++l) {
            int e4  = l * 256 + tid;
            int row = e4 >> 3;
            int c4  = (e4 & 7) << 2;
            float4 av = *(const float4*)&A[(size_t)(m0 + row) * K + k0 + c4];
            As[c4 + 0][row] = av.x; As[c4 + 1][row] = av.y;
            As[c4 + 2][row] = av.z; As[c4 + 3][row] = av.w;
            float4 wv = *(const float4*)&W[(size_t)(n0 + row) * K + k0 + c4];
            Bs[c4 + 0][row] = wv.x; Bs[c4 + 1][row] = wv.y;
            Bs[c4 + 2][row] = wv.z; Bs[c4 + 3][row] = wv.w;
        }
        __syncthreads();
        for (int kk = 0; kk < 32; ++kk) {
            float4 a0 = *(const float4*)&As[kk][8 * ty];
            float4 a1 = *(const float4*)&As[kk][8 * ty + 4];
            float4 b0 = *(const float4*)&Bs[kk][8 * tx];
            float4 b1 = *(const float4*)&Bs[kk][8 * tx + 4];
            float a[8] = {a0.x, a0.y, a0.z, a0.w, a1.x, a1.y, a1.z, a1.w};
            float b[8] = {b0.x, b0.y, b0.z, b0.w, b1.x, b1.y, b1.z, b1.w};
#pragma unroll
            for (int i = 0; i < 8; ++i)
#pragma unroll
                for (int j = 0; j < 8; ++j)
                    acc[i][j] = fmaf(a[i], b[j], acc[i][j]);
        }
        __syncthreads();
    }

#pragma unroll
    for (int i = 0; i < 8; ++i) {
        int m = m0 + 8 * ty + i;
#pragma unroll
        for (int j = 0; j < 8; ++j) {
            int n = n0 + 8 * tx + j;
            out[(size_t)m * DMODEL + n] = acc[i][j] + bias[n];
        }
    }
}

// ---------------------------------------------------------------------------
// Flash attention, fp32. One block = (b, h, 64-row Q tile). 256 threads,
// 16x16 thread layout, 4x4 micro-tile of the 64x64 S tile.
// ALiBi bias computed inline: slope_h = 2^(-(h+1)/2), bias = slope*(j-i).
// Causal: skip K tiles entirely past the diagonal; per-element mask on the
// diagonal tile. P reuses the K LDS buffer (K stored k-major, P stored j-major).
// ---------------------------------------------------------------------------

__global__ __launch_bounds__(256)
void attn_kernel(const float* __restrict__ q, const float* __restrict__ k,
                 const float* __restrict__ v, const int* __restrict__ causal_p,
                 float* __restrict__ y)
{
    const int qt = blockIdx.x;   // 0..31
    const int h  = blockIdx.y;   // 0..15
    const int b  = blockIdx.z;   // 0..1
    const int tid = threadIdx.x;
    const int ty = tid >> 4, tx = tid & 15;
    const int i0 = 4 * ty, j0 = 4 * tx;
    const int q0 = qt * 64;
    const int causal = causal_p[0];
    const float slope = exp2f(-0.5f * (float)(h + 1));

    __shared__ float Qs[64 * 68];   // [d][i]  (k-major)
    __shared__ float KPs[64 * 68];  // K: [d][j] ; later P: [j][i]
    __shared__ float Vs[64 * 68];   // [j][c]  (natural)

    const size_t base = (((size_t)b * NH + h) * SEQ) * HD;

    // Q tile, transposed + pre-scaled by 1/sqrt(hd)
#pragma unroll
    for (int l = 0; l < 16; ++l) {
        int e = l * 256 + tid;
        int r = e >> 6, d = e & 63;
        Qs[d * 68 + r] = q[base + (size_t)(q0 + r) * HD + d] * 0.125f;
    }

    float m_i[4], l_i[4], o[4][4];
#pragma unroll
    for (int i = 0; i < 4; ++i) {
        m_i[i] = -1e30f; l_i[i] = 0.f;
#pragma unroll
        for (int c = 0; c < 4; ++c) o[i][c] = 0.f;
    }

    const int ktmax = causal ? qt : (SEQ / 64 - 1);
    for (int kt = 0; kt <= ktmax; ++kt) {
        const int k0 = kt * 64;
        __syncthreads();   // previous iteration's P/V reads complete
        // K tile transposed
#pragma unroll
        for (int l = 0; l < 16; ++l) {
            int e = l * 256 + tid;
            int r = e >> 6, d = e & 63;
            KPs[d * 68 + r] = k[base + (size_t)(k0 + r) * HD + d];
        }
        // V tile natural, float4
#pragma unroll
        for (int l = 0; l < 4; ++l) {
            int e4 = l * 256 + tid;
            int r = e4 >> 4, c4 = (e4 & 15) << 2;
            *(float4*)&Vs[r * 68 + c4] =
                *(const float4*)&v[base + (size_t)(k0 + r) * HD + c4];
        }
        __syncthreads();

        // S = (Q*scale) K^T
        float s[4][4];
#pragma unroll
        for (int i = 0; i < 4; ++i)
#pragma unroll
            for (int j = 0; j < 4; ++j) s[i][j] = 0.f;
        for (int kk = 0; kk < 64; ++kk) {
            float4 qv = *(const float4*)&Qs[kk * 68 + i0];
            float4 kv = *(const float4*)&KPs[kk * 68 + j0];
            float qa[4] = {qv.x, qv.y, qv.z, qv.w};
            float kb[4] = {kv.x, kv.y, kv.z, kv.w};
#pragma unroll
            for (int i = 0; i < 4; ++i)
#pragma unroll
                for (int j = 0; j < 4; ++j)
                    s[i][j] = fmaf(qa[i], kb[j], s[i][j]);
        }

        // ALiBi bias + causal mask
#pragma unroll
        for (int i = 0; i < 4; ++i) {
            int gi = q0 + i0 + i;
#pragma unroll
            for (int j = 0; j < 4; ++j) {
                int gj = k0 + j0 + j;
                if (causal && gj > gi) s[i][j] = -1e30f;
                else                   s[i][j] += slope * (float)(gj - gi);
            }
        }

        // row max across the 16 threads of each row group
        float mt[4];
#pragma unroll
        for (int i = 0; i < 4; ++i)
            mt[i] = fmaxf(fmaxf(s[i][0], s[i][1]), fmaxf(s[i][2], s[i][3]));
#pragma unroll
        for (int off = 1; off < 16; off <<= 1)
#pragma unroll
            for (int i = 0; i < 4; ++i)
                mt[i] = fmaxf(mt[i], __shfl_xor(mt[i], off, 16));

        float alpha[4];
#pragma unroll
        for (int i = 0; i < 4; ++i) {
            float mn = fmaxf(m_i[i], mt[i]);
            alpha[i] = __expf(m_i[i] - mn);
            m_i[i] = mn;
        }

        // P = exp(S - m), row sums
        float ls[4];
#pragma unroll
        for (int i = 0; i < 4; ++i) {
            ls[i] = 0.f;
#pragma unroll
            for (int j = 0; j < 4; ++j) {
                s[i][j] = __expf(s[i][j] - m_i[i]);
                ls[i] += s[i][j];
            }
        }
#pragma unroll
        for (int off = 1; off < 16; off <<= 1)
#pragma unroll
            for (int i = 0; i < 4; ++i)
                ls[i] += __shfl_xor(ls[i], off, 16);
#pragma unroll
        for (int i = 0; i < 4; ++i) l_i[i] = l_i[i] * alpha[i] + ls[i];

        __syncthreads();   // everyone done reading KPs as K
        // write P transposed: P[j][i]
#pragma unroll
        for (int i = 0; i < 4; ++i)
#pragma unroll
            for (int j = 0; j < 4; ++j)
                KPs[(j0 + j) * 68 + (i0 + i)] = s[i][j];
        // rescale O
#pragma unroll
        for (int i = 0; i < 4; ++i)
#pragma unroll
            for (int c = 0; c < 4; ++c) o[i][c] *= alpha[i];
        __syncthreads();   // P visible

        // O += P V
        for (int j = 0; j < 64; ++j) {
            float4 pv = *(const float4*)&KPs[j * 68 + i0];
            float4 vv = *(const float4*)&Vs[j * 68 + j0];
            float pa[4] = {pv.x, pv.y, pv.z, pv.w};
            float vb[4] = {vv.x, vv.y, vv.z, vv.w};
#pragma unroll
            for (int i = 0; i < 4; ++i)
#pragma unroll
                for (int c = 0; c < 4; ++c)
                    o[i][c] = fmaf(pa[i], vb[c], o[i][c]);
        }
    }

    // write y in (B, T, D) layout, heads concatenated
#pragma unroll
    for (int i = 0; i < 4; ++i) {
        float inv_l = 1.0f / l_i[i];
#pragma unroll
        for (int c = 0; c < 4; ++c) {
            size_t idx = (size_t)(b * SEQ + q0 + i0 + i) * DMODEL + h * HD + j0 + c;
            y[idx] = o[i][c] * inv_l;
        }
    }
}

// ---------------------------------------------------------------------------

extern "C" void kernel_launch(void* const* d_in, const int* in_sizes, int n_in,
                              void* d_out, int out_size, void* d_ws, size_t ws_size,
                              hipStream_t stream)
{
    const float* x     = (const float*)d_in[0];
    const int*   caus  = (const int*)d_in[1];
    // d_in[2] = alibi_bias: deterministic, recomputed on device (saves 268 MB HBM read)
    const float* Wqkv  = (const float*)d_in[3];
    const float* bqkv  = (const float*)d_in[4];
    const float* Wout  = (const float*)d_in[5];
    const float* bout  = (const float*)d_in[6];
    float* out = (float*)d_out;

    float* ws = (float*)d_ws;
    const size_t per = (size_t)NB * NH * SEQ * HD;  // 4M floats
    float* qws = ws;
    float* kws = ws + per;
    float* vws = ws + 2 * per;
    float* yws = ws + 3 * per;   // (B, T, D)

    // 1) QKV projection: (4096 x 1024) @ (3072 x 1024)^T
    dim3 g1(3072 / 128, 4096 / 128);
    gemm_qkv_kernel<<<g1, 256, 0, stream>>>(x, Wqkv, bqkv, qws, kws, vws);

    // 2) flash attention
    dim3 ga(SEQ / 64, NH, NB);
    attn_kernel<<<ga, 256, 0, stream>>>(qws, kws, vws, caus, yws);

    // 3) output projection: (4096 x 1024) @ (1024 x 1024)^T
    dim3 g2(1024 / 128, 4096 / 128);
    gemm_out_kernel<<<g2, 256, 0, stream>>>(yws, Wout, bout, out);
}

// Round 2
// 525.874 us; speedup vs baseline: 2.5887x; 2.5887x over previous
//
#include <hip/hip_runtime.h>
#include <cstddef>
#include <cstdint>

#define SEQ    2048
#define DMODEL 1024
#define NH     16
#define HD     64
#define NB     2

typedef __attribute__((ext_vector_type(8))) short short8;
typedef __attribute__((ext_vector_type(4))) float floatx4;

#define MFMA16(a, b, c) __builtin_amdgcn_mfma_f32_16x16x32_bf16((a), (b), (c), 0, 0, 0)

// async 16B global->LDS (wave-uniform base + lane*16 ordering honored by callers)
#define ASYNC16(gsrc, ldst) \
    __builtin_amdgcn_global_load_lds((const __attribute__((address_space(1))) void*)(gsrc), \
                                     (__attribute__((address_space(3))) void*)(ldst), 16, 0, 0)

__device__ __forceinline__ short f2bf(float f) {
    union { float f; unsigned u; } a; a.f = f;
    unsigned u = a.u;
    unsigned r = u + 0x7fffu + ((u >> 16) & 1u);   // RNE
    return (short)(r >> 16);
}

// ---------------------------------------------------------------------------
// fp32 -> bf16 conversion for x, Wqkv, Wout (one pass, float4 -> short4)
// ---------------------------------------------------------------------------
#define NX4 1048576   // x: 4,194,304 elems / 4
#define NW4  786432   // Wqkv: 3,145,728 / 4
#define NO4  262144   // Wout: 1,048,576 / 4

__global__ __launch_bounds__(256)
void convert_kernel(const float* __restrict__ x, const float* __restrict__ wqkv,
                    const float* __restrict__ wout,
                    short* __restrict__ xb, short* __restrict__ wqkvb,
                    short* __restrict__ woutb)
{
    int i = blockIdx.x * 256 + threadIdx.x;
    const float* src; short* dst; int off;
    if (i < NX4)            { src = x;    dst = xb;    off = i; }
    else if (i < NX4 + NW4) { src = wqkv; dst = wqkvb; off = i - NX4; }
    else if (i < NX4 + NW4 + NO4) { src = wout; dst = woutb; off = i - NX4 - NW4; }
    else return;
    float4 f = ((const float4*)src)[off];
    short4 s;
    s.x = f2bf(f.x); s.y = f2bf(f.y); s.z = f2bf(f.z); s.w = f2bf(f.w);
    ((short4*)dst)[off] = s;
}

// ---------------------------------------------------------------------------
// bf16 MFMA GEMM: C = A (MxK) * W^T (NxK). 128x128 tile, BK=64, 256 thr = 4
// waves, each wave a 64x64 quadrant = 4x4 grid of 16x16x32 MFMA tiles.
// LDS tiles 128x64 bf16, XOR-swizzled 16B chunks: slot col8' = col8 ^ (row&7).
// Staged via global_load_lds (16B/lane, lane-order == LDS order).
// ---------------------------------------------------------------------------

__device__ __forceinline__ void gemm_stage(const short* __restrict__ A,
                                           const short* __restrict__ W,
                                           short* As, short* Bs,
                                           int m0, int n0, int k0, int K, int tid)
{
#pragma unroll
    for (int l = 0; l < 4; ++l) {
        int c = l * 256 + tid;
        int row = c >> 3;
        int col8 = (c & 7) ^ (row & 7);      // swizzled source chunk
        ASYNC16(&A[(size_t)(m0 + row) * K + k0 + col8 * 8], &As[c * 8]);
        ASYNC16(&W[(size_t)(n0 + row) * K + k0 + col8 * 8], &Bs[c * 8]);
    }
}

__device__ __forceinline__ void gemm_core(const short* As, const short* Bs,
                                          floatx4 acc[4][4], int wm, int wn,
                                          int l15, int quad)
{
#pragma unroll
    for (int kc = 0; kc < 2; ++kc) {
        short8 a[4], b[4];
#pragma unroll
        for (int t = 0; t < 4; ++t) {
            int rowa = wm * 64 + t * 16 + l15;
            int rowb = wn * 64 + t * 16 + l15;
            int sw = (kc * 4 + quad) ^ (l15 & 7);
            a[t] = *(const short8*)&As[(rowa * 8 + sw) * 8];
            b[t] = *(const short8*)&Bs[(rowb * 8 + sw) * 8];
        }
#pragma unroll
        for (int i = 0; i < 4; ++i)
#pragma unroll
            for (int j = 0; j < 4; ++j)
                acc[i][j] = MFMA16(a[i], b[j], acc[i][j]);
    }
}

__global__ __launch_bounds__(256)
void gemm_qkv_bf16(const short* __restrict__ A, const short* __restrict__ W,
                   const float* __restrict__ bias,
                   short* __restrict__ qws, short* __restrict__ kws,
                   short* __restrict__ vtws)
{
    __shared__ short As[128 * 64];
    __shared__ short Bs[128 * 64];
    const int tid = threadIdx.x;
    const int wave = tid >> 6, lane = tid & 63;
    const int l15 = lane & 15, quad = lane >> 4;
    const int wm = wave >> 1, wn = wave & 1;
    const int m0 = blockIdx.y * 128, n0 = blockIdx.x * 128;

    floatx4 acc[4][4];
#pragma unroll
    for (int i = 0; i < 4; ++i)
#pragma unroll
        for (int j = 0; j < 4; ++j) acc[i][j] = (floatx4){0.f, 0.f, 0.f, 0.f};

    for (int k0 = 0; k0 < DMODEL; k0 += 64) {
        __syncthreads();
        gemm_stage(A, W, As, Bs, m0, n0, k0, DMODEL, tid);
        __syncthreads();
        gemm_core(As, Bs, acc, wm, wn, l15, quad);
    }

    // epilogue: bias + scatter to q/k natural (B,H,T,hd) and v transposed (B,H,hd,T)
#pragma unroll
    for (int i = 0; i < 4; ++i) {
#pragma unroll
        for (int j = 0; j < 4; ++j) {
            int ntile = n0 + wn * 64 + j * 16;
            int n = ntile + l15;
            int which = n >> 10;
            int rr = n & 1023;
            int h = rr >> 6, d = rr & 63;
            float bv = bias[n];
#pragma unroll
            for (int r = 0; r < 4; ++r) {
                int m = m0 + wm * 64 + i * 16 + quad * 4 + r;
                int bb = m >> 11, t = m & 2047;
                short val = f2bf(acc[i][j][r] + bv);
                size_t hb = (size_t)(bb * NH + h);
                if (which == 0)      qws[(hb * SEQ + t) * HD + d] = val;
                else if (which == 1) kws[(hb * SEQ + t) * HD + d] = val;
                else                 vtws[(hb * HD + d) * SEQ + t] = val;
            }
        }
    }
}

__global__ __launch_bounds__(256)
void gemm_out_bf16(const short* __restrict__ A, const short* __restrict__ W,
                   const float* __restrict__ bias, float* __restrict__ out)
{
    __shared__ short As[128 * 64];
    __shared__ short Bs[128 * 64];
    const int tid = threadIdx.x;
    const int wave = tid >> 6, lane = tid & 63;
    const int l15 = lane & 15, quad = lane >> 4;
    const int wm = wave >> 1, wn = wave & 1;
    const int m0 = blockIdx.y * 128, n0 = blockIdx.x * 128;

    floatx4 acc[4][4];
#pragma unroll
    for (int i = 0; i < 4; ++i)
#pragma unroll
        for (int j = 0; j < 4; ++j) acc[i][j] = (floatx4){0.f, 0.f, 0.f, 0.f};

    for (int k0 = 0; k0 < DMODEL; k0 += 64) {
        __syncthreads();
        gemm_stage(A, W, As, Bs, m0, n0, k0, DMODEL, tid);
        __syncthreads();
        gemm_core(As, Bs, acc, wm, wn, l15, quad);
    }

#pragma unroll
    for (int i = 0; i < 4; ++i) {
#pragma unroll
        for (int j = 0; j < 4; ++j) {
            int n = n0 + wn * 64 + j * 16 + l15;
            float bv = bias[n];
#pragma unroll
            for (int r = 0; r < 4; ++r) {
                int m = m0 + wm * 64 + i * 16 + quad * 4 + r;
                out[(size_t)m * DMODEL + n] = acc[i][j][r] + bv;
            }
        }
    }
}

// ---------------------------------------------------------------------------
// MFMA flash attention. Block = (64 Q rows, h, b), 4 waves, wave = 16-row band.
// K tile 64 keys. QK^T: A=Q[m][d], B=K[n=key][d]. Softmax in C-layout regs.
// P -> wave-private LDS (bf16) to re-layout C->A. PV: B=V^T[n=d][k=key].
// ALiBi computed inline; causal tile-skip + diagonal mask.
// ---------------------------------------------------------------------------

__global__ __launch_bounds__(256)
void attn_mfma(const short* __restrict__ q, const short* __restrict__ k,
               const short* __restrict__ vt, const int* __restrict__ causal_p,
               short* __restrict__ y)
{
    const int qt = blockIdx.x, h = blockIdx.y, b = blockIdx.z;
    const int tid = threadIdx.x;
    const int wave = tid >> 6, lane = tid & 63;
    const int l15 = lane & 15, quad = lane >> 4;
    const int q0 = qt * 64;
    const int causal = causal_p[0];
    const float slope = exp2f(-0.5f * (float)(h + 1));

    __shared__ short Ks[64 * 64];       // [t][d], swizzled 16B chunks
    __shared__ short Vs[64 * 64];       // [d][t], swizzled
    __shared__ short Ps[4][16 * 64];    // per-wave P [row][key], swizzled

    const size_t base = ((size_t)(b * NH + h)) * SEQ * HD;   // q,k layout
    const size_t vbase = base;                                // vt: (B,H,hd,T)

    // Q fragments: A[m=l15][k = kc*32 + quad*8 + j], pre-loaded once
    short8 aq[2];
    {
        int qrow = q0 + wave * 16 + l15;
#pragma unroll
        for (int kc = 0; kc < 2; ++kc)
            aq[kc] = *(const short8*)&q[base + (size_t)qrow * HD + kc * 32 + quad * 8];
    }

    float m_i[4], l_i[4];
    floatx4 o[4];
#pragma unroll
    for (int r = 0; r < 4; ++r) { m_i[r] = -1e30f; l_i[r] = 0.f; }
#pragma unroll
    for (int dt = 0; dt < 4; ++dt) o[dt] = (floatx4){0.f, 0.f, 0.f, 0.f};

    const int ktmax = causal ? qt : (SEQ / 64 - 1);
    for (int kt = 0; kt <= ktmax; ++kt) {
        const int k0 = kt * 64;
        __syncthreads();
        // stage K tile [t][d] and V^T tile [d][t]: 512 chunks each, 2/thread
#pragma unroll
        for (int l = 0; l < 2; ++l) {
            int c = l * 256 + tid;
            int row = c >> 3;
            int col8 = (c & 7) ^ (row & 7);
            ASYNC16(&k[base + (size_t)(k0 + row) * HD + col8 * 8], &Ks[c * 8]);
            ASYNC16(&vt[vbase + (size_t)row * SEQ + k0 + col8 * 8], &Vs[c * 8]);
        }
        __syncthreads();

        // S = Q K^T  (4 col-tiles of 16 keys)
        floatx4 s[4];
#pragma unroll
        for (int ct = 0; ct < 4; ++ct) {
            int rowb = ct * 16 + l15;
            int sw0 = (quad) ^ (l15 & 7);
            int sw1 = (4 + quad) ^ (l15 & 7);
            short8 bk0 = *(const short8*)&Ks[(rowb * 8 + sw0) * 8];
            short8 bk1 = *(const short8*)&Ks[(rowb * 8 + sw1) * 8];
            floatx4 z = (floatx4){0.f, 0.f, 0.f, 0.f};
            z = MFMA16(aq[0], bk0, z);
            z = MFMA16(aq[1], bk1, z);
            s[ct] = z;
        }

        // scale + ALiBi + causal mask; row max
        const int gi_base = q0 + wave * 16 + quad * 4;
        float mnew[4];
#pragma unroll
        for (int r = 0; r < 4; ++r) {
            int gi = gi_base + r;
            float mx = -1e30f;
#pragma unroll
            for (int ct = 0; ct < 4; ++ct) {
                int gj = k0 + ct * 16 + l15;
                float sv = s[ct][r] * 0.125f + slope * (float)(gj - gi);
                if (causal && gj > gi) sv = -1e30f;
                s[ct][r] = sv;
                mx = fmaxf(mx, sv);
            }
            mnew[r] = mx;
        }
#pragma unroll
        for (int off = 1; off < 16; off <<= 1)
#pragma unroll
            for (int r = 0; r < 4; ++r)
                mnew[r] = fmaxf(mnew[r], __shfl_xor(mnew[r], off, 64));

        float alpha[4], ls[4];
#pragma unroll
        for (int r = 0; r < 4; ++r) {
            float mn = fmaxf(m_i[r], mnew[r]);
            alpha[r] = __expf(m_i[r] - mn);
            m_i[r] = mn;
            ls[r] = 0.f;
#pragma unroll
            for (int ct = 0; ct < 4; ++ct) {
                float p = __expf(s[ct][r] - mn);
                s[ct][r] = p;
                ls[r] += p;
            }
        }
#pragma unroll
        for (int off = 1; off < 16; off <<= 1)
#pragma unroll
            for (int r = 0; r < 4; ++r)
                ls[r] += __shfl_xor(ls[r], off, 64);
#pragma unroll
        for (int r = 0; r < 4; ++r) l_i[r] = l_i[r] * alpha[r] + ls[r];

        // P -> wave-private LDS (C-layout -> A-layout), bf16
        short* Pw = &Ps[wave][0];
#pragma unroll
        for (int ct = 0; ct < 4; ++ct) {
#pragma unroll
            for (int r = 0; r < 4; ++r) {
                int row = quad * 4 + r;
                int col = ct * 16 + l15;
                Pw[(row * 8 + ((col >> 3) ^ (row & 7))) * 8 + (col & 7)] = f2bf(s[ct][r]);
            }
        }
        asm volatile("s_waitcnt lgkmcnt(0)" ::: "memory");  // wave-private RAW

        // A fragments of P: m = l15, k = kc*32 + quad*8
        int swp0 = (quad) ^ (l15 & 7);
        int swp1 = (4 + quad) ^ (l15 & 7);
        short8 ap0 = *(const short8*)&Pw[(l15 * 8 + swp0) * 8];
        short8 ap1 = *(const short8*)&Pw[(l15 * 8 + swp1) * 8];

        // O = O*alpha + P V
#pragma unroll
        for (int dt = 0; dt < 4; ++dt) {
            int rowv = dt * 16 + l15;
            short8 bv0 = *(const short8*)&Vs[(rowv * 8 + swp0) * 8];
            short8 bv1 = *(const short8*)&Vs[(rowv * 8 + swp1) * 8];
            floatx4 oo = o[dt];
#pragma unroll
            for (int r = 0; r < 4; ++r) oo[r] *= alpha[r];
            oo = MFMA16(ap0, bv0, oo);
            oo = MFMA16(ap1, bv1, oo);
            o[dt] = oo;
        }
    }

    // epilogue: y (B,T,D) bf16
#pragma unroll
    for (int dt = 0; dt < 4; ++dt) {
#pragma unroll
        for (int r = 0; r < 4; ++r) {
            int row = q0 + wave * 16 + quad * 4 + r;
            int col = h * HD + dt * 16 + l15;
            y[(size_t)(b * SEQ + row) * DMODEL + col] = f2bf(o[dt][r] / l_i[r]);
        }
    }
}

// ---------------------------------------------------------------------------

extern "C" void kernel_launch(void* const* d_in, const int* in_sizes, int n_in,
                              void* d_out, int out_size, void* d_ws, size_t ws_size,
                              hipStream_t stream)
{
    const float* x    = (const float*)d_in[0];
    const int*   caus = (const int*)d_in[1];
    // d_in[2] = alibi_bias: recomputed on device
    const float* Wqkv = (const float*)d_in[3];
    const float* bqkv = (const float*)d_in[4];
    const float* Wout = (const float*)d_in[5];
    const float* bout = (const float*)d_in[6];
    float* out = (float*)d_out;

    char* ws = (char*)d_ws;
    short* xb    = (short*)(ws);                       // 8 MB
    short* wqkvb = (short*)(ws + (8u  << 20));         // 6 MB
    short* woutb = (short*)(ws + (14u << 20));         // 2 MB
    short* qws   = (short*)(ws + (16u << 20));         // 8 MB
    short* kws   = (short*)(ws + (24u << 20));         // 8 MB
    short* vtws  = (short*)(ws + (32u << 20));         // 8 MB
    short* yb    = (short*)(ws + (40u << 20));         // 8 MB

    convert_kernel<<<8192, 256, 0, stream>>>(x, Wqkv, Wout, xb, wqkvb, woutb);

    dim3 g1(3072 / 128, 4096 / 128);
    gemm_qkv_bf16<<<g1, 256, 0, stream>>>(xb, wqkvb, bqkv, qws, kws, vtws);

    dim3 ga(SEQ / 64, NH, NB);
    attn_mfma<<<ga, 256, 0, stream>>>(qws, kws, vtws, caus, yb);

    dim3 g2(1024 / 128, 4096 / 128);
    gemm_out_bf16<<<g2, 256, 0, stream>>>(yb, woutb, bout, out);
}